// Round 9
// baseline (357.962 us; speedup 1.0000x reference)
//
#include <hip/hip_runtime.h>
#include <stdint.h>

// AttentionBlock: GN -> QKV -> softmax(QK^T/sqrt(C)) V -> proj + residual
// B=4, C=256, H=W=64, N=4096, groups=8 (32 ch/group)
// All matmuls bf16 MFMA (fp32 accumulate). fp32 threshold 0.1 absmax.
//
// Round 9: register blocking in attn. W=2 waves x R=32 q-rows (64 rows/blk,
// grid 256): every K/V fragment read from LDS now feeds 2 MFMAs -> per-CU
// LDS read traffic halves (was the 13%-MfmaUtil ceiling). V swizzle fixed to
// (ch>>1)&3 (read bank-groups tile all 8); plds padded to 40 u16/row.

#define B_ 4
#define C_ 256
#define N_ 4096
#define KVB 32

using bf16x8 = __attribute__((ext_vector_type(8))) __bf16;
using f32x4  = __attribute__((ext_vector_type(4))) float;

__device__ __forceinline__ uint16_t f2bf(float f) {
    uint32_t u = __float_as_uint(f);
    u = (u + 0x7fffu + ((u >> 16) & 1u)) >> 16;   // RNE
    return (uint16_t)u;
}

__device__ __forceinline__ f32x4 mfma16(bf16x8 a, bf16x8 b, f32x4 c) {
    return __builtin_amdgcn_mfma_f32_16x16x32_bf16(a, b, c, 0, 0, 0);
}

__device__ __forceinline__ void gload16(const void* g, void* l) {
    __builtin_amdgcn_global_load_lds(
        (const __attribute__((address_space(1))) uint32_t*)g,
        (__attribute__((address_space(3))) uint32_t*)l, 16, 0, 0);
}

// ---------------- cast weights to bf16 ----------------
__global__ __launch_bounds__(256) void cast_weights(
        const float* __restrict__ qkvw, const float* __restrict__ projw,
        uint16_t* __restrict__ qkvwb, uint16_t* __restrict__ projwb) {
    int i = blockIdx.x * 256 + threadIdx.x;
    if (i < 768 * 256) qkvwb[i] = f2bf(qkvw[i]);
    int j = i - 768 * 256;
    if (j >= 0 && j < 256 * 256) projwb[j] = f2bf(projw[j]);
}

// ---------------- GroupNorm stats, two-stage ----------------
__global__ __launch_bounds__(256) void gn_stats1(const float* __restrict__ x,
                                                 float2* __restrict__ part) {
    int i = blockIdx.x;
    const float4* p = reinterpret_cast<const float4*>(x + (size_t)i * 4096);
    float s = 0.f, ss = 0.f;
    #pragma unroll
    for (int j = 0; j < 4; j++) {
        float4 v = p[threadIdx.x + j * 256];
        s  += v.x + v.y + v.z + v.w;
        ss += v.x*v.x + v.y*v.y + v.z*v.z + v.w*v.w;
    }
    #pragma unroll
    for (int d = 32; d > 0; d >>= 1) { s += __shfl_down(s, d); ss += __shfl_down(ss, d); }
    __shared__ float rs[4], rss[4];
    int wid = threadIdx.x >> 6;
    if ((threadIdx.x & 63) == 0) { rs[wid] = s; rss[wid] = ss; }
    __syncthreads();
    if (threadIdx.x == 0) {
        float2 o;
        o.x = rs[0] + rs[1] + rs[2] + rs[3];
        o.y = rss[0] + rss[1] + rss[2] + rss[3];
        part[i] = o;
    }
}
__global__ __launch_bounds__(1024) void gn_stats2(const float2* __restrict__ part,
                                                  float* __restrict__ stats) {
    int t = threadIdx.x;
    int g = t >> 5, j = t & 31;
    float2 v = part[g * 32 + j];
    float s = v.x, ss = v.y;
    #pragma unroll
    for (int d = 16; d > 0; d >>= 1) { s += __shfl_xor(s, d); ss += __shfl_xor(ss, d); }
    if (j == 0) {
        float mean = s / 131072.f;
        float var  = ss / 131072.f - mean * mean;
        stats[g * 2]     = mean;
        stats[g * 2 + 1] = rsqrtf(var + 1e-5f);
    }
}

// ---------------- GN apply + transpose: hT[b][n][c] bf16 ----------------
__global__ __launch_bounds__(256) void gn_apply(
        const float* __restrict__ x, const float* __restrict__ gnw,
        const float* __restrict__ gnb, const float* __restrict__ stats,
        uint16_t* __restrict__ hT) {
    int nb = blockIdx.x * 64, cb = blockIdx.y * 64, b = blockIdx.z;
    __shared__ uint16_t lds[64][64];          // [n][c]
    int t = threadIdx.x;
    int c_l = t >> 4;
    int n4  = (t & 15) * 4;
    #pragma unroll
    for (int i = 0; i < 4; i++) {
        int c = cb + c_l + 16 * i;
        int sg = b * 8 + (c >> 5);
        float mean = stats[sg * 2], rstd = stats[sg * 2 + 1];
        float sc = gnw[c] * rstd;
        float sh = gnb[c] - mean * sc;
        float4 v = *reinterpret_cast<const float4*>(x + ((size_t)b * C_ + c) * N_ + nb + n4);
        lds[n4 + 0][c_l + 16 * i] = f2bf(fmaf(v.x, sc, sh));
        lds[n4 + 1][c_l + 16 * i] = f2bf(fmaf(v.y, sc, sh));
        lds[n4 + 2][c_l + 16 * i] = f2bf(fmaf(v.z, sc, sh));
        lds[n4 + 3][c_l + 16 * i] = f2bf(fmaf(v.w, sc, sh));
    }
    __syncthreads();
    int n_l = t >> 2, c16 = (t & 3) * 16;
    uint4* dst = reinterpret_cast<uint4*>(hT + ((size_t)b * N_ + nb + n_l) * C_ + cb + c16);
    const uint4* sp = reinterpret_cast<const uint4*>(&lds[n_l][c16]);
    dst[0] = sp[0]; dst[1] = sp[1];
}

// ---------------- QKV GEMM ----------------
// q,k transposed [n][o]; q pre-scaled by 1/16 (softmax scale). v kept [o'][n].
__global__ __launch_bounds__(256) void qkv_gemm(
        const uint16_t* __restrict__ Wb, const float* __restrict__ qkvb,
        const uint16_t* __restrict__ hT, uint16_t* __restrict__ qT,
        uint16_t* __restrict__ kT, uint16_t* __restrict__ vO) {
    int nt = blockIdx.x, ot = blockIdx.y, b = blockIdx.z;
    int lane = threadIdx.x & 63, w = threadIdx.x >> 6;
    int l15 = lane & 15, g = lane >> 4;
    const uint16_t* hTb = hT + (size_t)b * N_ * C_;
    f32x4 z = {0.f, 0.f, 0.f, 0.f};
    f32x4 acc[4] = {z, z, z, z};

    if (ot < 8) {   // q,k : D[row=n][col=o]
        int nrow = nt * 64 + w * 16 + l15;
        const bf16x8* Arow = reinterpret_cast<const bf16x8*>(hTb + (size_t)nrow * C_);
        #pragma unroll
        for (int kk = 0; kk < 8; kk++) {
            bf16x8 a = Arow[kk * 4 + g];
            #pragma unroll
            for (int j = 0; j < 4; j++) {
                int orow = ot * 64 + j * 16 + l15;
                bf16x8 bfr = reinterpret_cast<const bf16x8*>(Wb + (size_t)orow * C_)[kk * 4 + g];
                acc[j] = mfma16(a, bfr, acc[j]);
            }
        }
        #pragma unroll
        for (int j = 0; j < 4; j++) {
            int o = ot * 64 + j * 16 + l15;
            float bias = qkvb[o];
            bool isq = (o < 256);
            float scl = isq ? 0.0625f : 1.0f;
            uint16_t* dst = isq ? (qT + (size_t)b * N_ * C_ + o)
                                : (kT + (size_t)b * N_ * C_ + (o - 256));
            #pragma unroll
            for (int r = 0; r < 4; r++) {
                int n = nt * 64 + w * 16 + g * 4 + r;
                dst[(size_t)n * C_] = f2bf((acc[j][r] + bias) * scl);
            }
        }
    } else {        // v : D[row=o'][col=n]
        int orow = ot * 64 + w * 16 + l15;   // 512..767
        const bf16x8* Arow = reinterpret_cast<const bf16x8*>(Wb + (size_t)orow * C_);
        #pragma unroll
        for (int kk = 0; kk < 8; kk++) {
            bf16x8 a = Arow[kk * 4 + g];
            #pragma unroll
            for (int j = 0; j < 4; j++) {
                int nrow = nt * 64 + j * 16 + l15;
                bf16x8 bfr = reinterpret_cast<const bf16x8*>(hTb + (size_t)nrow * C_)[kk * 4 + g];
                acc[j] = mfma16(a, bfr, acc[j]);
            }
        }
        #pragma unroll
        for (int j = 0; j < 4; j++) {
            #pragma unroll
            for (int r = 0; r < 4; r++) {
                int o = ot * 64 + w * 16 + g * 4 + r;
                int n = nt * 64 + j * 16 + l15;
                vO[(size_t)b * C_ * N_ + (size_t)(o - 512) * N_ + n] = f2bf(acc[j][r] + qkvb[o]);
            }
        }
    }
}

// ---------------- Flash attention: 2 waves x 32 q-rows, static-max ----------
// Block: 128 thr = 2 waves; wave w owns rows nb+w*32 .. +32 (2 rowgroups of
// 16). Both waves sweep the same 32-key LDS tiles (double-buffered,
// global_load_lds w16). Each K/V fragment read feeds 2 MFMAs (2 rowgroups) ->
// half the LDS read traffic of the 4-wave R=16 version.
//   K tile [32 r][32 chunk], chunk' = chunk ^ (r&7)       (phase-uniform)
//   V tile [256 ch][4 chunk], chunk' = chunk ^ ((ch>>1)&3) (phase-uniform)
//   plds rows padded to 40 u16 (80B) -> b16 writes 2-way (free), b128 read
//   bank-groups (l15*5+g)%8 tile all 8.
__global__ __launch_bounds__(128, 1) void attn_kernel(
        const uint16_t* __restrict__ qT, const uint16_t* __restrict__ kT,
        const uint16_t* __restrict__ vO, uint16_t* __restrict__ h2T) {
    int blk = blockIdx.x;
    int xx = blk & 7;
    int b  = xx >> 1;
    int qt = (blk >> 3) * 2 + (xx & 1);       // 0..63
    int lane = threadIdx.x & 63, w = threadIdx.x >> 6;   // w in {0,1}
    int l15 = lane & 15, g = lane >> 4;
    const uint16_t* qTb = qT + (size_t)b * N_ * C_;
    const uint16_t* kTb = kT + (size_t)b * N_ * C_;
    const uint16_t* vb  = vO + (size_t)b * C_ * N_;
    int nb = qt * 64 + w * 32;

    __shared__ uint16_t Kt[2][32 * 256];      // 32 KB
    __shared__ uint16_t Vt[2][256 * 32];      // 32 KB
    __shared__ uint16_t plds[2][2][16][40];   // 5 KB, wave-private, padded rows

    // Q fragments for both rowgroups (once)
    bf16x8 afr0[8], afr1[8];
    {
        const bf16x8* q0 = reinterpret_cast<const bf16x8*>(qTb + (size_t)(nb + l15) * C_);
        const bf16x8* q1 = reinterpret_cast<const bf16x8*>(qTb + (size_t)(nb + 16 + l15) * C_);
        #pragma unroll
        for (int kk = 0; kk < 8; kk++) { afr0[kk] = q0[kk * 4 + g]; afr1[kk] = q1[kk * 4 + g]; }
    }

    f32x4 z = {0.f, 0.f, 0.f, 0.f};
    f32x4 acc0[16], acc1[16];
    #pragma unroll
    for (int i = 0; i < 16; i++) { acc0[i] = z; acc1[i] = z; }
    float l0[4] = {0.f, 0.f, 0.f, 0.f};
    float l1[4] = {0.f, 0.f, 0.f, 0.f};

    auto stage = [&](int buf, int mb) {
        // K: wave w stages rows [w*16, w*16+16): 8 instrs x 2 rows
        #pragma unroll
        for (int i = 0; i < 8; i++) {
            int rb = w * 16 + i * 2;
            int r  = rb + (lane >> 5);
            int c  = (lane & 31) ^ (r & 7);
            gload16(kTb + (size_t)(mb + r) * C_ + c * 8, &Kt[buf][rb * 256]);
        }
        // V: wave w stages channels [w*128, w*128+128): 8 instrs x 16 ch
        #pragma unroll
        for (int i = 0; i < 8; i++) {
            int cb2 = w * 128 + i * 16;
            int ch = cb2 + (lane >> 2);
            int c  = (lane & 3) ^ ((ch >> 1) & 3);
            gload16(vb + (size_t)ch * N_ + mb + c * 8, &Vt[buf][cb2 * 32]);
        }
    };

    stage(0, 0);
    __syncthreads();

    for (int mt = 0; mt < 128; mt++) {
        int buf = mt & 1;
        if (mt + 1 < 128) stage(buf ^ 1, (mt + 1) * KVB);

        // ---- QK^T: each K fragment feeds both rowgroups ----
        f32x4 s00 = z, s01 = z, s10 = z, s11 = z;
        #pragma unroll
        for (int kk = 0; kk < 8; kk++) {
            int c0 = (kk * 4 + g) ^ (l15 & 7);
            bf16x8 k0 = *reinterpret_cast<const bf16x8*>(&Kt[buf][l15 * 256 + c0 * 8]);
            bf16x8 k1 = *reinterpret_cast<const bf16x8*>(&Kt[buf][(16 + l15) * 256 + c0 * 8]);
            s00 = mfma16(afr0[kk], k0, s00);
            s01 = mfma16(afr0[kk], k1, s01);
            s10 = mfma16(afr1[kk], k0, s10);
            s11 = mfma16(afr1[kk], k1, s11);
        }

        // ---- static-max softmax (scores pre-scaled via qT) ----
        #pragma unroll
        for (int r = 0; r < 4; r++) {
            float p0 = __expf(s00[r]), p1 = __expf(s01[r]);
            l0[r] += p0 + p1;
            plds[w][0][g * 4 + r][l15]      = f2bf(p0);
            plds[w][0][g * 4 + r][16 + l15] = f2bf(p1);
            float q0 = __expf(s10[r]), q1 = __expf(s11[r]);
            l1[r] += q0 + q1;
            plds[w][1][g * 4 + r][l15]      = f2bf(q0);
            plds[w][1][g * 4 + r][16 + l15] = f2bf(q1);
        }
        // plds is wave-private: no barrier, compiler inserts lgkm waits

        bf16x8 pb0 = *reinterpret_cast<const bf16x8*>(&plds[w][0][l15][g * 8]);
        bf16x8 pb1 = *reinterpret_cast<const bf16x8*>(&plds[w][1][l15][g * 8]);

        // ---- PV: each V fragment feeds both rowgroups ----
        #pragma unroll
        for (int ct = 0; ct < 16; ct++) {
            int ch = ct * 16 + l15;
            bf16x8 va = *reinterpret_cast<const bf16x8*>(
                &Vt[buf][ch * 32 + ((g ^ ((l15 >> 1) & 3)) * 8)]);
            acc0[ct] = mfma16(va, pb0, acc0[ct]);
            acc1[ct] = mfma16(va, pb1, acc1[ct]);
        }

        __syncthreads();   // drains vmcnt (stage done) + both waves done with buf
    }

    // ---- epilogue: reduce l partials, normalize, direct u32-pair stores ----
    #pragma unroll
    for (int d = 1; d < 16; d <<= 1) {
        #pragma unroll
        for (int r = 0; r < 4; r++) { l0[r] += __shfl_xor(l0[r], d); l1[r] += __shfl_xor(l1[r], d); }
    }
    int bsrc = (l15 >> 2) * 16;
    int sel = l15 & 3;
    float a0 = __shfl(l0[0], bsrc), a1 = __shfl(l0[1], bsrc),
          a2 = __shfl(l0[2], bsrc), a3 = __shfl(l0[3], bsrc);
    float lv0 = (sel == 0) ? a0 : (sel == 1) ? a1 : (sel == 2) ? a2 : a3;
    float b0 = __shfl(l1[0], bsrc), b1 = __shfl(l1[1], bsrc),
          b2 = __shfl(l1[2], bsrc), b3 = __shfl(l1[3], bsrc);
    float lv1 = (sel == 0) ? b0 : (sel == 1) ? b1 : (sel == 2) ? b2 : b3;
    float inv0 = 1.0f / lv0, inv1 = 1.0f / lv1;

    uint16_t* row0 = h2T + ((size_t)b * N_ + nb + l15) * C_;
    uint16_t* row1 = h2T + ((size_t)b * N_ + nb + 16 + l15) * C_;
    #pragma unroll
    for (int ct = 0; ct < 16; ct++) {
        uint32_t lo0 = f2bf(acc0[ct][0] * inv0) | ((uint32_t)f2bf(acc0[ct][1] * inv0) << 16);
        uint32_t hi0 = f2bf(acc0[ct][2] * inv0) | ((uint32_t)f2bf(acc0[ct][3] * inv0) << 16);
        *reinterpret_cast<uint32_t*>(row0 + ct * 16 + g * 4)     = lo0;
        *reinterpret_cast<uint32_t*>(row0 + ct * 16 + g * 4 + 2) = hi0;
        uint32_t lo1 = f2bf(acc1[ct][0] * inv1) | ((uint32_t)f2bf(acc1[ct][1] * inv1) << 16);
        uint32_t hi1 = f2bf(acc1[ct][2] * inv1) | ((uint32_t)f2bf(acc1[ct][3] * inv1) << 16);
        *reinterpret_cast<uint32_t*>(row1 + ct * 16 + g * 4)     = lo1;
        *reinterpret_cast<uint32_t*>(row1 + ct * 16 + g * 4 + 2) = hi1;
    }
}

// ---------------- proj GEMM + bias + residual ----------------
__global__ __launch_bounds__(256) void proj_gemm(
        const uint16_t* __restrict__ Pwb, const float* __restrict__ pb,
        const uint16_t* __restrict__ h2T, const float* __restrict__ x,
        float* __restrict__ out) {
    int nt = blockIdx.x, ct = blockIdx.y, b = blockIdx.z;
    int lane = threadIdx.x & 63, w = threadIdx.x >> 6;
    int l15 = lane & 15, g = lane >> 4;
    const uint16_t* h2Tb = h2T + (size_t)b * N_ * C_;
    f32x4 z = {0.f, 0.f, 0.f, 0.f};
    f32x4 acc[4] = {z, z, z, z};
    int crow = ct * 64 + w * 16 + l15;
    const bf16x8* Arow = reinterpret_cast<const bf16x8*>(Pwb + (size_t)crow * C_);
    #pragma unroll
    for (int kk = 0; kk < 8; kk++) {
        bf16x8 a = Arow[kk * 4 + g];
        #pragma unroll
        for (int j = 0; j < 4; j++) {
            bf16x8 bfr = reinterpret_cast<const bf16x8*>(
                h2Tb + (size_t)(nt * 64 + j * 16 + l15) * C_)[kk * 4 + g];
            acc[j] = mfma16(a, bfr, acc[j]);
        }
    }
    #pragma unroll
    for (int j = 0; j < 4; j++) {
        #pragma unroll
        for (int r = 0; r < 4; r++) {
            int c = ct * 64 + w * 16 + g * 4 + r;
            int n = nt * 64 + j * 16 + l15;
            size_t idx = ((size_t)b * C_ + c) * N_ + n;
            out[idx] = x[idx] + acc[j][r] + pb[c];
        }
    }
}

extern "C" void kernel_launch(void* const* d_in, const int* in_sizes, int n_in,
                              void* d_out, int out_size, void* d_ws, size_t ws_size,
                              hipStream_t stream) {
    const float* x      = (const float*)d_in[0];
    const float* gn_w   = (const float*)d_in[1];
    const float* gn_b   = (const float*)d_in[2];
    const float* qkv_w  = (const float*)d_in[3];
    const float* qkv_b  = (const float*)d_in[4];
    const float* proj_w = (const float*)d_in[5];
    const float* proj_b = (const float*)d_in[6];
    float* out = (float*)d_out;

    char* ws = (char*)d_ws;
    float*    stats  = (float*)(ws);                          // 256 B
    float2*   part   = (float2*)(ws + 8192);                  // 8 KB
    uint16_t* qkvwb  = (uint16_t*)(ws + 65536);               // 384 KB
    uint16_t* projwb = (uint16_t*)(ws + 65536 + 768 * 256 * 2);
    uint16_t* hT     = (uint16_t*)(ws + (size_t)(1)  * (1 << 20));  // 8 MB [B][N][C]
    uint16_t* qT     = (uint16_t*)(ws + (size_t)(9)  * (1 << 20));  // 8 MB [B][N][C]
    uint16_t* kT     = (uint16_t*)(ws + (size_t)(17) * (1 << 20));  // 8 MB [B][N][C]
    uint16_t* vO     = (uint16_t*)(ws + (size_t)(25) * (1 << 20));  // 8 MB [B][C][N]
    uint16_t* h2T    = (uint16_t*)(ws + (size_t)(33) * (1 << 20));  // 8 MB [B][N][C]

    cast_weights<<<dim3(1024), dim3(256), 0, stream>>>(qkv_w, proj_w, qkvwb, projwb);
    gn_stats1<<<dim3(1024), dim3(256), 0, stream>>>(x, part);
    gn_stats2<<<dim3(1), dim3(1024), 0, stream>>>(part, stats);
    gn_apply<<<dim3(64, 4, 4), dim3(256), 0, stream>>>(x, gn_w, gn_b, stats, hT);
    qkv_gemm<<<dim3(64, 12, 4), dim3(256), 0, stream>>>(qkvwb, qkv_b, hT, qT, kT, vO);
    attn_kernel<<<dim3(256), dim3(128), 0, stream>>>(qT, kT, vO, h2T);
    proj_gemm<<<dim3(64, 4, 4), dim3(256), 0, stream>>>(projwb, proj_b, h2T, x, out);
}

// Round 10
// 221.771 us; speedup vs baseline: 1.6141x; 1.6141x over previous
//
#include <hip/hip_runtime.h>
#include <stdint.h>

// AttentionBlock: GN -> QKV -> softmax(QK^T/sqrt(C)) V -> proj + residual
// B=4, C=256, H=W=64, N=4096, groups=8 (32 ch/group)
// All matmuls bf16 MFMA (fp32 accumulate). fp32 threshold 0.1 absmax.
//
// Round 10: 8-wave attn block (512 thr) = 2 waves/SIMD. 4 rowgroups x 16
// rows; key-split 2-way (half h = w>>2 sweeps 64 of 128 tiles) with per-half
// double-buffered K/V LDS (138 KB total). Static-max softmax -> trivial
// merge (O=O0+O1, l=l0+l1) in epilogue via LDS (reuses Kt as fp32 buffer).
// Fixes round 9's half-idle CU (2 waves/CU) while keeping low conflicts.

#define B_ 4
#define C_ 256
#define N_ 4096
#define KVB 32

using bf16x8 = __attribute__((ext_vector_type(8))) __bf16;
using f32x4  = __attribute__((ext_vector_type(4))) float;

__device__ __forceinline__ uint16_t f2bf(float f) {
    uint32_t u = __float_as_uint(f);
    u = (u + 0x7fffu + ((u >> 16) & 1u)) >> 16;   // RNE
    return (uint16_t)u;
}

__device__ __forceinline__ f32x4 mfma16(bf16x8 a, bf16x8 b, f32x4 c) {
    return __builtin_amdgcn_mfma_f32_16x16x32_bf16(a, b, c, 0, 0, 0);
}

__device__ __forceinline__ void gload16(const void* g, void* l) {
    __builtin_amdgcn_global_load_lds(
        (const __attribute__((address_space(1))) uint32_t*)g,
        (__attribute__((address_space(3))) uint32_t*)l, 16, 0, 0);
}

// ---------------- cast weights to bf16 ----------------
__global__ __launch_bounds__(256) void cast_weights(
        const float* __restrict__ qkvw, const float* __restrict__ projw,
        uint16_t* __restrict__ qkvwb, uint16_t* __restrict__ projwb) {
    int i = blockIdx.x * 256 + threadIdx.x;
    if (i < 768 * 256) qkvwb[i] = f2bf(qkvw[i]);
    int j = i - 768 * 256;
    if (j >= 0 && j < 256 * 256) projwb[j] = f2bf(projw[j]);
}

// ---------------- GroupNorm stats, two-stage ----------------
__global__ __launch_bounds__(256) void gn_stats1(const float* __restrict__ x,
                                                 float2* __restrict__ part) {
    int i = blockIdx.x;
    const float4* p = reinterpret_cast<const float4*>(x + (size_t)i * 4096);
    float s = 0.f, ss = 0.f;
    #pragma unroll
    for (int j = 0; j < 4; j++) {
        float4 v = p[threadIdx.x + j * 256];
        s  += v.x + v.y + v.z + v.w;
        ss += v.x*v.x + v.y*v.y + v.z*v.z + v.w*v.w;
    }
    #pragma unroll
    for (int d = 32; d > 0; d >>= 1) { s += __shfl_down(s, d); ss += __shfl_down(ss, d); }
    __shared__ float rs[4], rss[4];
    int wid = threadIdx.x >> 6;
    if ((threadIdx.x & 63) == 0) { rs[wid] = s; rss[wid] = ss; }
    __syncthreads();
    if (threadIdx.x == 0) {
        float2 o;
        o.x = rs[0] + rs[1] + rs[2] + rs[3];
        o.y = rss[0] + rss[1] + rss[2] + rss[3];
        part[i] = o;
    }
}
__global__ __launch_bounds__(1024) void gn_stats2(const float2* __restrict__ part,
                                                  float* __restrict__ stats) {
    int t = threadIdx.x;
    int g = t >> 5, j = t & 31;
    float2 v = part[g * 32 + j];
    float s = v.x, ss = v.y;
    #pragma unroll
    for (int d = 16; d > 0; d >>= 1) { s += __shfl_xor(s, d); ss += __shfl_xor(ss, d); }
    if (j == 0) {
        float mean = s / 131072.f;
        float var  = ss / 131072.f - mean * mean;
        stats[g * 2]     = mean;
        stats[g * 2 + 1] = rsqrtf(var + 1e-5f);
    }
}

// ---------------- GN apply + transpose: hT[b][n][c] bf16 ----------------
__global__ __launch_bounds__(256) void gn_apply(
        const float* __restrict__ x, const float* __restrict__ gnw,
        const float* __restrict__ gnb, const float* __restrict__ stats,
        uint16_t* __restrict__ hT) {
    int nb = blockIdx.x * 64, cb = blockIdx.y * 64, b = blockIdx.z;
    __shared__ uint16_t lds[64][64];          // [n][c]
    int t = threadIdx.x;
    int c_l = t >> 4;
    int n4  = (t & 15) * 4;
    #pragma unroll
    for (int i = 0; i < 4; i++) {
        int c = cb + c_l + 16 * i;
        int sg = b * 8 + (c >> 5);
        float mean = stats[sg * 2], rstd = stats[sg * 2 + 1];
        float sc = gnw[c] * rstd;
        float sh = gnb[c] - mean * sc;
        float4 v = *reinterpret_cast<const float4*>(x + ((size_t)b * C_ + c) * N_ + nb + n4);
        lds[n4 + 0][c_l + 16 * i] = f2bf(fmaf(v.x, sc, sh));
        lds[n4 + 1][c_l + 16 * i] = f2bf(fmaf(v.y, sc, sh));
        lds[n4 + 2][c_l + 16 * i] = f2bf(fmaf(v.z, sc, sh));
        lds[n4 + 3][c_l + 16 * i] = f2bf(fmaf(v.w, sc, sh));
    }
    __syncthreads();
    int n_l = t >> 2, c16 = (t & 3) * 16;
    uint4* dst = reinterpret_cast<uint4*>(hT + ((size_t)b * N_ + nb + n_l) * C_ + cb + c16);
    const uint4* sp = reinterpret_cast<const uint4*>(&lds[n_l][c16]);
    dst[0] = sp[0]; dst[1] = sp[1];
}

// ---------------- QKV GEMM ----------------
// q,k transposed [n][o]; q pre-scaled by 1/16 (softmax scale). v kept [o'][n].
__global__ __launch_bounds__(256) void qkv_gemm(
        const uint16_t* __restrict__ Wb, const float* __restrict__ qkvb,
        const uint16_t* __restrict__ hT, uint16_t* __restrict__ qT,
        uint16_t* __restrict__ kT, uint16_t* __restrict__ vO) {
    int nt = blockIdx.x, ot = blockIdx.y, b = blockIdx.z;
    int lane = threadIdx.x & 63, w = threadIdx.x >> 6;
    int l15 = lane & 15, g = lane >> 4;
    const uint16_t* hTb = hT + (size_t)b * N_ * C_;
    f32x4 z = {0.f, 0.f, 0.f, 0.f};
    f32x4 acc[4] = {z, z, z, z};

    if (ot < 8) {   // q,k : D[row=n][col=o]
        int nrow = nt * 64 + w * 16 + l15;
        const bf16x8* Arow = reinterpret_cast<const bf16x8*>(hTb + (size_t)nrow * C_);
        #pragma unroll
        for (int kk = 0; kk < 8; kk++) {
            bf16x8 a = Arow[kk * 4 + g];
            #pragma unroll
            for (int j = 0; j < 4; j++) {
                int orow = ot * 64 + j * 16 + l15;
                bf16x8 bfr = reinterpret_cast<const bf16x8*>(Wb + (size_t)orow * C_)[kk * 4 + g];
                acc[j] = mfma16(a, bfr, acc[j]);
            }
        }
        #pragma unroll
        for (int j = 0; j < 4; j++) {
            int o = ot * 64 + j * 16 + l15;
            float bias = qkvb[o];
            bool isq = (o < 256);
            float scl = isq ? 0.0625f : 1.0f;
            uint16_t* dst = isq ? (qT + (size_t)b * N_ * C_ + o)
                                : (kT + (size_t)b * N_ * C_ + (o - 256));
            #pragma unroll
            for (int r = 0; r < 4; r++) {
                int n = nt * 64 + w * 16 + g * 4 + r;
                dst[(size_t)n * C_] = f2bf((acc[j][r] + bias) * scl);
            }
        }
    } else {        // v : D[row=o'][col=n]
        int orow = ot * 64 + w * 16 + l15;   // 512..767
        const bf16x8* Arow = reinterpret_cast<const bf16x8*>(Wb + (size_t)orow * C_);
        #pragma unroll
        for (int kk = 0; kk < 8; kk++) {
            bf16x8 a = Arow[kk * 4 + g];
            #pragma unroll
            for (int j = 0; j < 4; j++) {
                int nrow = nt * 64 + j * 16 + l15;
                bf16x8 bfr = reinterpret_cast<const bf16x8*>(hTb + (size_t)nrow * C_)[kk * 4 + g];
                acc[j] = mfma16(a, bfr, acc[j]);
            }
        }
        #pragma unroll
        for (int j = 0; j < 4; j++) {
            #pragma unroll
            for (int r = 0; r < 4; r++) {
                int o = ot * 64 + w * 16 + g * 4 + r;
                int n = nt * 64 + j * 16 + l15;
                vO[(size_t)b * C_ * N_ + (size_t)(o - 512) * N_ + n] = f2bf(acc[j][r] + qkvb[o]);
            }
        }
    }
}

// ---------------- Flash attention: 8 waves, 2-way key split ----------------
// Block: 512 thr = 8 waves. Wave w: rowgroup rg = w&3 (rows nb+rg*16),
// key half h = w>>2 (tiles h*64+i, i=0..63). Per-half double-buffered K/V in
// LDS (Kt/Vt[2][half]); 64 iterations; barrier per iter syncs both halves.
// Static-max softmax (m=0, q pre-scaled): p=exp(s), per-lane l partials.
// Epilogue: half 1 writes (O,l) to LDS (Kt region reused as fp32), half 0
// merges (O0+O1, l0+l1), normalizes, stores h2T[n][c].
//   K tile [32 r][32 chunk16B], chunk' = chunk ^ (r&7)
//   V tile [256 ch][4 chunk16B], chunk' = chunk ^ ((ch>>1)&3)
//   plds rows padded to 40 u16 -> b128 read bank-groups (l15*5+g)%8 tile all 8
__global__ __launch_bounds__(512, 2) void attn_kernel(
        const uint16_t* __restrict__ qT, const uint16_t* __restrict__ kT,
        const uint16_t* __restrict__ vO, uint16_t* __restrict__ h2T) {
    int blk = blockIdx.x;
    int xx = blk & 7;
    int b  = xx >> 1;
    int qt = (blk >> 3) * 2 + (xx & 1);       // 0..63
    int lane = threadIdx.x & 63, w = threadIdx.x >> 6;   // w in 0..7
    int rg = w & 3, h = w >> 2;
    int l15 = lane & 15, g = lane >> 4;
    const uint16_t* qTb = qT + (size_t)b * N_ * C_;
    const uint16_t* kTb = kT + (size_t)b * N_ * C_;
    const uint16_t* vb  = vO + (size_t)b * C_ * N_;
    int nb = qt * 64 + rg * 16;

    __shared__ uint16_t Kt[2][2][32 * 256];   // [buf][half], 64 KB
    __shared__ uint16_t Vt[2][2][256 * 32];   // [buf][half], 64 KB
    __shared__ uint16_t plds[8][16][40];      // 10 KB, wave-private padded

    // Q fragments (once)
    bf16x8 afr[8];
    {
        const bf16x8* qrow = reinterpret_cast<const bf16x8*>(qTb + (size_t)(nb + l15) * C_);
        #pragma unroll
        for (int kk = 0; kk < 8; kk++) afr[kk] = qrow[kk * 4 + g];
    }

    f32x4 z = {0.f, 0.f, 0.f, 0.f};
    f32x4 acc[16];
    #pragma unroll
    for (int i = 0; i < 16; i++) acc[i] = z;
    float l_r[4] = {0.f, 0.f, 0.f, 0.f};

    // wave w stages its half's next tile: K rows rg*8..+8, V ch rg*64..+64
    auto stage = [&](int buf, int mb) {
        #pragma unroll
        for (int i = 0; i < 4; i++) {
            int rb = rg * 8 + i * 2;
            int r  = rb + (lane >> 5);
            int c  = (lane & 31) ^ (r & 7);
            gload16(kTb + (size_t)(mb + r) * C_ + c * 8, &Kt[buf][h][rb * 256]);
        }
        #pragma unroll
        for (int i = 0; i < 4; i++) {
            int cb2 = rg * 64 + i * 16;
            int ch = cb2 + (lane >> 2);
            int c  = (lane & 3) ^ ((ch >> 1) & 3);
            gload16(vb + (size_t)ch * N_ + mb + c * 8, &Vt[buf][h][cb2 * 32]);
        }
    };

    stage(0, h * 64 * KVB);
    __syncthreads();

    for (int mt = 0; mt < 64; mt++) {
        int buf = mt & 1;
        if (mt + 1 < 64) stage(buf ^ 1, (h * 64 + mt + 1) * KVB);

        // ---- QK^T from this half's K tile ----
        f32x4 sc0 = z, sc1 = z;
        #pragma unroll
        for (int kk = 0; kk < 8; kk++) {
            int c0 = (kk * 4 + g) ^ (l15 & 7);
            bf16x8 k0 = *reinterpret_cast<const bf16x8*>(&Kt[buf][h][l15 * 256 + c0 * 8]);
            bf16x8 k1 = *reinterpret_cast<const bf16x8*>(&Kt[buf][h][(16 + l15) * 256 + c0 * 8]);
            sc0 = mfma16(afr[kk], k0, sc0);
            sc1 = mfma16(afr[kk], k1, sc1);
        }

        // ---- static-max softmax ----
        #pragma unroll
        for (int r = 0; r < 4; r++) {
            float p0 = __expf(sc0[r]);
            float p1 = __expf(sc1[r]);
            l_r[r] += p0 + p1;
            plds[w][g * 4 + r][l15]      = f2bf(p0);
            plds[w][g * 4 + r][16 + l15] = f2bf(p1);
        }
        // plds wave-private: no barrier needed

        bf16x8 pb = *reinterpret_cast<const bf16x8*>(&plds[w][l15][g * 8]);

        // ---- PV from this half's V tile ----
        #pragma unroll
        for (int ct = 0; ct < 16; ct++) {
            int ch = ct * 16 + l15;
            bf16x8 va = *reinterpret_cast<const bf16x8*>(
                &Vt[buf][h][ch * 32 + ((g ^ ((ch >> 1) & 3)) * 8)]);
            acc[ct] = mfma16(va, pb, acc[ct]);
        }

        __syncthreads();   // drains vmcnt; both halves advance together
    }

    // ---- reduce l partials within wave; map to per-lane q-row = l15 ----
    #pragma unroll
    for (int d = 1; d < 16; d <<= 1) {
        #pragma unroll
        for (int r = 0; r < 4; r++) l_r[r] += __shfl_xor(l_r[r], d);
    }
    int bsrc = (l15 >> 2) * 16;
    int sel = l15 & 3;
    float s0 = __shfl(l_r[0], bsrc), s1 = __shfl(l_r[1], bsrc),
          s2 = __shfl(l_r[2], bsrc), s3 = __shfl(l_r[3], bsrc);
    float lv = (sel == 0) ? s0 : (sel == 1) ? s1 : (sel == 2) ? s2 : s3;

    // ---- cross-half merge via LDS (reuse Kt as fp32 O-buffer, Vt for l) ----
    float* Olds = reinterpret_cast<float*>(&Kt[0][0][0]);   // [64 rows][256 ch] f32
    float* lbuf = reinterpret_cast<float*>(&Vt[0][0][0]);   // [64] f32
    if (h == 1) {
        if (lane < 16) lbuf[rg * 16 + l15] = lv;
        #pragma unroll
        for (int ct = 0; ct < 16; ct++)
            *reinterpret_cast<f32x4*>(&Olds[(size_t)(rg * 16 + l15) * 256 + ct * 16 + g * 4]) = acc[ct];
    }
    __syncthreads();
    if (h == 0) {
        float inv = 1.0f / (lv + lbuf[rg * 16 + l15]);
        uint16_t* row = h2T + ((size_t)b * N_ + nb + l15) * C_;
        #pragma unroll
        for (int ct = 0; ct < 16; ct++) {
            f32x4 o2 = *reinterpret_cast<const f32x4*>(
                &Olds[(size_t)(rg * 16 + l15) * 256 + ct * 16 + g * 4]);
            uint32_t lo = f2bf((acc[ct][0] + o2[0]) * inv) |
                          ((uint32_t)f2bf((acc[ct][1] + o2[1]) * inv) << 16);
            uint32_t hi = f2bf((acc[ct][2] + o2[2]) * inv) |
                          ((uint32_t)f2bf((acc[ct][3] + o2[3]) * inv) << 16);
            *reinterpret_cast<uint32_t*>(row + ct * 16 + g * 4)     = lo;
            *reinterpret_cast<uint32_t*>(row + ct * 16 + g * 4 + 2) = hi;
        }
    }
}

// ---------------- proj GEMM + bias + residual ----------------
__global__ __launch_bounds__(256) void proj_gemm(
        const uint16_t* __restrict__ Pwb, const float* __restrict__ pb,
        const uint16_t* __restrict__ h2T, const float* __restrict__ x,
        float* __restrict__ out) {
    int nt = blockIdx.x, ct = blockIdx.y, b = blockIdx.z;
    int lane = threadIdx.x & 63, w = threadIdx.x >> 6;
    int l15 = lane & 15, g = lane >> 4;
    const uint16_t* h2Tb = h2T + (size_t)b * N_ * C_;
    f32x4 z = {0.f, 0.f, 0.f, 0.f};
    f32x4 acc[4] = {z, z, z, z};
    int crow = ct * 64 + w * 16 + l15;
    const bf16x8* Arow = reinterpret_cast<const bf16x8*>(Pwb + (size_t)crow * C_);
    #pragma unroll
    for (int kk = 0; kk < 8; kk++) {
        bf16x8 a = Arow[kk * 4 + g];
        #pragma unroll
        for (int j = 0; j < 4; j++) {
            bf16x8 bfr = reinterpret_cast<const bf16x8*>(
                h2Tb + (size_t)(nt * 64 + j * 16 + l15) * C_)[kk * 4 + g];
            acc[j] = mfma16(a, bfr, acc[j]);
        }
    }
    #pragma unroll
    for (int j = 0; j < 4; j++) {
        #pragma unroll
        for (int r = 0; r < 4; r++) {
            int c = ct * 64 + w * 16 + g * 4 + r;
            int n = nt * 64 + j * 16 + l15;
            size_t idx = ((size_t)b * C_ + c) * N_ + n;
            out[idx] = x[idx] + acc[j][r] + pb[c];
        }
    }
}

extern "C" void kernel_launch(void* const* d_in, const int* in_sizes, int n_in,
                              void* d_out, int out_size, void* d_ws, size_t ws_size,
                              hipStream_t stream) {
    const float* x      = (const float*)d_in[0];
    const float* gn_w   = (const float*)d_in[1];
    const float* gn_b   = (const float*)d_in[2];
    const float* qkv_w  = (const float*)d_in[3];
    const float* qkv_b  = (const float*)d_in[4];
    const float* proj_w = (const float*)d_in[5];
    const float* proj_b = (const float*)d_in[6];
    float* out = (float*)d_out;

    char* ws = (char*)d_ws;
    float*    stats  = (float*)(ws);                          // 256 B
    float2*   part   = (float2*)(ws + 8192);                  // 8 KB
    uint16_t* qkvwb  = (uint16_t*)(ws + 65536);               // 384 KB
    uint16_t* projwb = (uint16_t*)(ws + 65536 + 768 * 256 * 2);
    uint16_t* hT     = (uint16_t*)(ws + (size_t)(1)  * (1 << 20));  // 8 MB [B][N][C]
    uint16_t* qT     = (uint16_t*)(ws + (size_t)(9)  * (1 << 20));  // 8 MB [B][N][C]
    uint16_t* kT     = (uint16_t*)(ws + (size_t)(17) * (1 << 20));  // 8 MB [B][N][C]
    uint16_t* vO     = (uint16_t*)(ws + (size_t)(25) * (1 << 20));  // 8 MB [B][C][N]
    uint16_t* h2T    = (uint16_t*)(ws + (size_t)(33) * (1 << 20));  // 8 MB [B][N][C]

    cast_weights<<<dim3(1024), dim3(256), 0, stream>>>(qkv_w, proj_w, qkvwb, projwb);
    gn_stats1<<<dim3(1024), dim3(256), 0, stream>>>(x, part);
    gn_stats2<<<dim3(1), dim3(1024), 0, stream>>>(part, stats);
    gn_apply<<<dim3(64, 4, 4), dim3(256), 0, stream>>>(x, gn_w, gn_b, stats, hT);
    qkv_gemm<<<dim3(64, 12, 4), dim3(256), 0, stream>>>(qkvwb, qkv_b, hT, qT, kT, vO);
    attn_kernel<<<dim3(256), dim3(512), 0, stream>>>(qT, kT, vO, h2T);
    proj_gemm<<<dim3(64, 4, 4), dim3(256), 0, stream>>>(projwb, proj_b, h2T, x, out);
}